// Round 1
// 4103.646 us; speedup vs baseline: 1.4045x; 1.4045x over previous
//
#include <hip/hip_runtime.h>

typedef __attribute__((ext_vector_type(8))) short short8;
typedef __attribute__((ext_vector_type(4))) float f32x4;

#define D_DIM 1024
#define BS 64
#define TSTEPS 512
#define NWG 256

// ---------------------------------------------------------------------------
// Persistent-recurrence design (R1):
//   - ONE kernel, 256 WGs x 1 wave, all co-resident (64KB LDS -> 2 WG/CU cap).
//   - W_rec fragments (hi/lo bf16) live in 256 VGPRs per wave (packed once).
//   - State ping-pong planes in global, stored in MFMA A-fragment order
//     [bblk][kc][lane][8] so the per-step read is a linear stream staged to
//     LDS via async global_load_lds (width 16).
//   - Device-scope barrier: agent-relaxed atomic stores (land at LLC, no
//     dirty L2 / no wbl2), sharded arrival counters (8 cachelines), relaxed
//     poll + one agent acquire fence (inv) per step.
// ---------------------------------------------------------------------------

// state planes: [plane][bblk(4)][kc(32)][lane(64)][elem(8)] hi / lo bf16
__device__ unsigned short g_s_hi[2][4 * 32 * 64 * 8];   // 2 x 128 KB
__device__ unsigned short g_s_lo[2][4 * 32 * 64 * 8];
// sharded barrier counters, one per 128B line; reset by ext_gemm each replay
__device__ unsigned g_cnt[8 * 32];

__device__ __forceinline__ unsigned short f2bf(float f){
    union { float f; unsigned u; } v; v.f = f;
    unsigned r = v.u + 0x7FFFu + ((v.u >> 16) & 1u);   // RNE
    return (unsigned short)(r >> 16);
}
__device__ __forceinline__ float bf2f(unsigned short h){
    union { unsigned u; float f; } v; v.u = ((unsigned)h) << 16;
    return v.f;
}
__device__ __forceinline__ void split1(float f, unsigned short& h, unsigned short& l){
    h = f2bf(f);
    l = f2bf(f - bf2f(h));
}
__device__ __forceinline__ void split8(const float* __restrict__ p, short8& h8, short8& l8){
    float4 f0 = *(const float4*)p;
    float4 f1 = *(const float4*)(p + 4);
    float v[8] = {f0.x, f0.y, f0.z, f0.w, f1.x, f1.y, f1.z, f1.w};
#pragma unroll
    for (int i = 0; i < 8; ++i){
        unsigned short h, l; split1(v[i], h, l);
        h8[i] = (short)h; l8[i] = (short)l;
    }
}

// fragment-order index for state element (batch b, feature-as-k o)
__device__ __forceinline__ int fidx(int b, int o){
    return ((((b >> 4) * 32 + (o >> 5)) * 64) + (b & 15) + ((o >> 3) & 3) * 16) * 8 + (o & 7);
}

// async 16B global->LDS (per-lane src, linear wave dest = base + lane*16)
__device__ __forceinline__ void gl_lds16(const unsigned short* g, unsigned short* l){
    __builtin_amdgcn_global_load_lds(
        (__attribute__((address_space(1))) void*)(unsigned long long)(g),
        (__attribute__((address_space(3))) void*)(unsigned int)(unsigned long long)(l),
        16, 0, 0);
}

// device-scope barrier; VM = vmcnt level that guarantees all prior STATE
// stores are drained before arrival (4 when exactly 4 ext-prefetch loads
// were issued after the stores, else 0).
template<int VM>
__device__ __forceinline__ void gbar(int j, int L, unsigned tgt){
    if constexpr (VM == 4) asm volatile("s_waitcnt vmcnt(4)" ::: "memory");
    else                   asm volatile("s_waitcnt vmcnt(0)" ::: "memory");
    if (L == 0)
        __hip_atomic_fetch_add(&g_cnt[(j & 7) * 32], 1u,
                               __ATOMIC_RELAXED, __HIP_MEMORY_SCOPE_AGENT);
    int s;
    for (;;){
        s = (int)__hip_atomic_load(&g_cnt[(L & 7) * 32],
                                   __ATOMIC_RELAXED, __HIP_MEMORY_SCOPE_AGENT);
        s += __shfl_xor(s, 1);
        s += __shfl_xor(s, 2);
        s += __shfl_xor(s, 4);
        if ((unsigned)s >= tgt) break;
        __builtin_amdgcn_s_sleep(2);
    }
    __builtin_amdgcn_fence(__ATOMIC_ACQUIRE, "agent");
}

// ---------------- ext[r][o] = sum_j x[r][j]*Win[o][j], fp32, r = b*512+t.
// Byte-identical numerics to the passing version; + barrier-counter reset.
__global__ __launch_bounds__(256) void ext_gemm(
    const float* __restrict__ x, const float* __restrict__ Win,
    float* __restrict__ ext)
{
    if (blockIdx.x == 0 && blockIdx.y == 0 && threadIdx.x < 8)
        g_cnt[threadIdx.x * 32] = 0;                 // reset before recurrence

    __shared__ unsigned short Ah[64 * 40];
    __shared__ unsigned short Al[64 * 40];
    const int tid = threadIdx.x;
    const int w = tid >> 6, L = tid & 63, lh = L & 15, q = L >> 4;
    const int m0 = blockIdx.y * 64;
    const int n0 = blockIdx.x * 64 + w * 16;
    const int r_st = tid >> 2, k8 = (tid & 3) * 8;

    f32x4 acc0 = {0,0,0,0}, acc1 = {0,0,0,0}, acc2 = {0,0,0,0}, acc3 = {0,0,0,0};

    for (int kc = 0; kc < 32; ++kc){
        short8 ash, asl;
        split8(x + (size_t)(m0 + r_st) * D_DIM + kc * 32 + k8, ash, asl);
        short8 bh, bl;
        split8(Win + (size_t)(n0 + lh) * D_DIM + kc * 32 + q * 8, bh, bl);
        *(short8*)&Ah[r_st * 40 + k8] = ash;
        *(short8*)&Al[r_st * 40 + k8] = asl;
        __syncthreads();
#pragma unroll
        for (int ms = 0; ms < 4; ++ms){
            short8 ah = *(const short8*)&Ah[(ms * 16 + lh) * 40 + q * 8];
            short8 al = *(const short8*)&Al[(ms * 16 + lh) * 40 + q * 8];
            f32x4* acc = (ms == 0) ? &acc0 : (ms == 1) ? &acc1 : (ms == 2) ? &acc2 : &acc3;
            *acc = __builtin_amdgcn_mfma_f32_16x16x32_bf16(ah, bh, *acc, 0, 0, 0);
            *acc = __builtin_amdgcn_mfma_f32_16x16x32_bf16(ah, bl, *acc, 0, 0, 0);
            *acc = __builtin_amdgcn_mfma_f32_16x16x32_bf16(al, bh, *acc, 0, 0, 0);
        }
        __syncthreads();
    }

    const int col = n0 + lh;
#pragma unroll
    for (int ms = 0; ms < 4; ++ms){
        f32x4 a = (ms == 0) ? acc0 : (ms == 1) ? acc1 : (ms == 2) ? acc2 : acc3;
#pragma unroll
        for (int r = 0; r < 4; ++r){
            int row = m0 + ms * 16 + q * 4 + r;
            ext[(size_t)row * D_DIM + col] = a[r];
        }
    }
}

// ---------------- persistent recurrence: all 512 steps in one launch.
// WG j: features fg*16.. (fg=j>>2), batches bg*16.. (bg=j&3). 1 wave.
// NOTE: ext aliases out (no __restrict__ here on purpose).
__global__ __launch_bounds__(64, 1) void recurrence(
    const float* ext, const float* Wrec, float* out)
{
    __shared__ __align__(16) unsigned short st_hi[32 * 64 * 8];  // 32 KB
    __shared__ __align__(16) unsigned short st_lo[32 * 64 * 8];  // 32 KB

    const int L = threadIdx.x, lh = L & 15, q = L >> 4;
    const int j = blockIdx.x;
    const int fg = j >> 2, bg = j & 3;
    const int b0 = bg * 16;
    const int o  = fg * 16 + lh;

    // ---- pack W_rec B-fragments (hi/lo) into registers: 64 x short8
    short8 WH[32], WL[32];
#pragma unroll
    for (int kc = 0; kc < 32; ++kc)
        split8(Wrec + (size_t)(fg * 16 + lh) * D_DIM + kc * 32 + q * 8, WH[kc], WL[kc]);

    // ---- init: v0 = e0 into plane 0 (agent-scope stores -> LLC)
#pragma unroll
    for (int r = 0; r < 4; ++r){
        int b = b0 + q * 4 + r;
        float f = ext[(size_t)b * (TSTEPS * D_DIM) + o];
        unsigned short h, l; split1(f, h, l);
        int fi = fidx(b, o);
        __hip_atomic_store(&g_s_hi[0][fi], h, __ATOMIC_RELAXED, __HIP_MEMORY_SCOPE_AGENT);
        __hip_atomic_store(&g_s_lo[0][fi], l, __ATOMIC_RELAXED, __HIP_MEMORY_SCOPE_AGENT);
    }
    asm volatile("" ::: "memory");          // keep stores before prefetch loads

    float ev[4];                             // prefetch e_1
#pragma unroll
    for (int r = 0; r < 4; ++r)
        ev[r] = ext[(size_t)(b0 + q * 4 + r) * (TSTEPS * D_DIM) + D_DIM + o];

    gbar<4>(j, L, 256u * 1);

#pragma unroll 1
    for (int k = 0; k < TSTEPS; ++k){
        const int p = k & 1;

        // ---- stage state slab (own 16 batches, full K) into LDS, async
        const unsigned short* gh = &g_s_hi[p][(bg * 32) * 512 + L * 8];
        const unsigned short* gl = &g_s_lo[p][(bg * 32) * 512 + L * 8];
#pragma unroll
        for (int i = 0; i < 32; ++i){
            gl_lds16(gh + i * 512, &st_hi[i * 512]);
            gl_lds16(gl + i * 512, &st_lo[i * 512]);
        }
        asm volatile("s_waitcnt vmcnt(0)" ::: "memory");
        __builtin_amdgcn_sched_barrier(0);

        // ---- 96 MFMAs: v @ Wrec^T (hi/lo 3-term, same as passing version)
        f32x4 aHH = {0,0,0,0}, aHL = {0,0,0,0}, aLH = {0,0,0,0};
#pragma unroll
        for (int kc = 0; kc < 32; ++kc){
            short8 ah = *(const short8*)&st_hi[kc * 512 + L * 8];
            short8 al = *(const short8*)&st_lo[kc * 512 + L * 8];
            aHH = __builtin_amdgcn_mfma_f32_16x16x32_bf16(ah, WH[kc], aHH, 0, 0, 0);
            aHL = __builtin_amdgcn_mfma_f32_16x16x32_bf16(ah, WL[kc], aHL, 0, 0, 0);
            aLH = __builtin_amdgcn_mfma_f32_16x16x32_bf16(al, WH[kc], aLH, 0, 0, 0);
        }

        if (k == TSTEPS - 1){
            // final state -> out[:,0,:] directly, full fp32 (no bf16 trip)
#pragma unroll
            for (int r = 0; r < 4; ++r){
                int b = b0 + q * 4 + r;
                out[(size_t)b * (TSTEPS * D_DIM) + o] =
                    fmaxf(aHH[r] + aHL[r] + aLH[r], 0.f);
            }
        } else {
            const int wp = p ^ 1;
#pragma unroll
            for (int r = 0; r < 4; ++r){
                int b = b0 + q * 4 + r;
                float f = fmaxf(aHH[r] + aHL[r] + aLH[r], 0.f) + ev[r];
                unsigned short h, l; split1(f, h, l);
                int fi = fidx(b, o);
                __hip_atomic_store(&g_s_hi[wp][fi], h, __ATOMIC_RELAXED, __HIP_MEMORY_SCOPE_AGENT);
                __hip_atomic_store(&g_s_lo[wp][fi], l, __ATOMIC_RELAXED, __HIP_MEMORY_SCOPE_AGENT);
            }
            asm volatile("" ::: "memory");  // stores strictly before prefetch
            if (k + 2 < TSTEPS){
                // prefetch e_{k+2}; its latency hides under the barrier spin
#pragma unroll
                for (int r = 0; r < 4; ++r)
                    ev[r] = ext[(size_t)(b0 + q * 4 + r) * (TSTEPS * D_DIM)
                                + (size_t)(k + 2) * D_DIM + o];
                gbar<4>(j, L, 256u * (unsigned)(k + 2));
            } else {
                gbar<0>(j, L, 256u * (unsigned)(k + 2));
            }
        }
    }
}

// ---------------- out[:,1:,:] = 0 (out[:,0,:] holds the final state)
__global__ __launch_bounds__(256) void zero_rest(float* __restrict__ out)
{
    size_t i4 = (size_t)blockIdx.x * 256 + threadIdx.x;  // float4 index
    size_t f = i4 * 4;
    int t = (int)((f >> 10) & 511);
    if (t == 0) return;                                   // out[:,0,:] kept
    *(float4*)(out + f) = make_float4(0.f, 0.f, 0.f, 0.f);
}

extern "C" void kernel_launch(void* const* d_in, const int* in_sizes, int n_in,
                              void* d_out, int out_size, void* d_ws, size_t ws_size,
                              hipStream_t stream) {
    const float* x     = (const float*)d_in[0];   // [64][512][1024]
    const float* W_in  = (const float*)d_in[1];   // [1024][1024]
    const float* W_rec = (const float*)d_in[2];   // [1024][1024]
    float* out = (float*)d_out;

    // ext (fp32, [b][t][o]) lives in d_out — dead space until the end.
    float* ext = out;

    // 1) input projection (+ resets barrier counters for this replay)
    ext_gemm<<<dim3(16, 512), 256, 0, stream>>>(x, W_in, ext);

    // 2) all 512 recurrence steps in ONE persistent kernel
    recurrence<<<NWG, 64, 0, stream>>>(ext, W_rec, out);

    // 3) zero everything except out[:,0,:]
    zero_rest<<<32768, 256, 0, stream>>>(out);
}

// Round 4
// 3292.334 us; speedup vs baseline: 1.7505x; 1.2464x over previous
//
#include <hip/hip_runtime.h>

typedef __attribute__((ext_vector_type(8))) short short8;
typedef __attribute__((ext_vector_type(4))) float f32x4;

#define D_DIM 1024
#define BS 64
#define TSTEPS 512
#define NWG 256

// ---------------------------------------------------------------------------
// R4 (= R2 design, compile-fixed): persistent recurrence, latency-trimmed.
//   - State planes are declared as unsigned long long natively so the 8-byte
//     agent-scope atomic stores are correctly typed/aligned (the R3 compile
//     failed on -Werror,-Watomic-alignment from a short*->ull* cast).
//   - 4 independent bg-group barriers (64 arrivals each, 8 sharded lines).
//   - Producer tile (16x16) is contiguous 512B/plane in fragment order:
//     LDS-transpose then 2x8B coalesced agent stores per lane.
//   - Transpose scratch aliases the head of the state slab (disjoint live
//     windows) -> LDS stays at exactly 65536 B (R1's HW-verified size).
//   - Staging: 64 global_load_lds issued up front, consumed in 4 chunks
//     gated by counted vmcnt (48/32/16/0) so MFMA overlaps the LDS fill.
//   - kc accumulation order unchanged -> bit-identical numerics.
// ---------------------------------------------------------------------------

// state planes: [plane][bg(4)][kc(32)][lane(64)][8 bf16] hi / lo.
// Declared as ull (4 shorts each) so 8B atomic stores are well-typed.
__device__ __align__(16) unsigned long long g_s_hi[2][16384];  // 2 x 128 KB
__device__ __align__(16) unsigned long long g_s_lo[2][16384];
// per-group sharded barrier counters: [grp(4)][shard(8)] one per 128B line
__device__ unsigned g_cnt[4 * 8 * 32];

__device__ __forceinline__ unsigned short f2bf(float f){
    union { float f; unsigned u; } v; v.f = f;
    unsigned r = v.u + 0x7FFFu + ((v.u >> 16) & 1u);   // RNE
    return (unsigned short)(r >> 16);
}
__device__ __forceinline__ float bf2f(unsigned short h){
    union { unsigned u; float f; } v; v.u = ((unsigned)h) << 16;
    return v.f;
}
__device__ __forceinline__ void split1(float f, unsigned short& h, unsigned short& l){
    h = f2bf(f);
    l = f2bf(f - bf2f(h));
}
__device__ __forceinline__ void split8(const float* __restrict__ p, short8& h8, short8& l8){
    float4 f0 = *(const float4*)p;
    float4 f1 = *(const float4*)(p + 4);
    float v[8] = {f0.x, f0.y, f0.z, f0.w, f1.x, f1.y, f1.z, f1.w};
#pragma unroll
    for (int i = 0; i < 8; ++i){
        unsigned short h, l; split1(v[i], h, l);
        h8[i] = (short)h; l8[i] = (short)l;
    }
}

// async 16B global->LDS (per-lane src, linear wave dest = base + lane*16)
__device__ __forceinline__ void gl_lds16(const unsigned short* g, unsigned short* l){
    __builtin_amdgcn_global_load_lds(
        (__attribute__((address_space(1))) void*)(unsigned long long)(g),
        (__attribute__((address_space(3))) void*)(unsigned int)(unsigned long long)(l),
        16, 0, 0);
}

// ---------------- ext[r][o] = sum_j x[r][j]*Win[o][j], fp32, r = b*512+t.
// Unchanged numerics; also resets the 32 barrier-counter lines each replay.
__global__ __launch_bounds__(256) void ext_gemm(
    const float* __restrict__ x, const float* __restrict__ Win,
    float* __restrict__ ext)
{
    if (blockIdx.x == 0 && blockIdx.y == 0 && threadIdx.x < 32)
        g_cnt[threadIdx.x * 32] = 0;                 // reset before recurrence

    __shared__ unsigned short Ah[64 * 40];
    __shared__ unsigned short Al[64 * 40];
    const int tid = threadIdx.x;
    const int w = tid >> 6, L = tid & 63, lh = L & 15, q = L >> 4;
    const int m0 = blockIdx.y * 64;
    const int n0 = blockIdx.x * 64 + w * 16;
    const int r_st = tid >> 2, k8 = (tid & 3) * 8;

    f32x4 acc0 = {0,0,0,0}, acc1 = {0,0,0,0}, acc2 = {0,0,0,0}, acc3 = {0,0,0,0};

    for (int kc = 0; kc < 32; ++kc){
        short8 ash, asl;
        split8(x + (size_t)(m0 + r_st) * D_DIM + kc * 32 + k8, ash, asl);
        short8 bh, bl;
        split8(Win + (size_t)(n0 + lh) * D_DIM + kc * 32 + q * 8, bh, bl);
        *(short8*)&Ah[r_st * 40 + k8] = ash;
        *(short8*)&Al[r_st * 40 + k8] = asl;
        __syncthreads();
#pragma unroll
        for (int ms = 0; ms < 4; ++ms){
            short8 ah = *(const short8*)&Ah[(ms * 16 + lh) * 40 + q * 8];
            short8 al = *(const short8*)&Al[(ms * 16 + lh) * 40 + q * 8];
            f32x4* acc = (ms == 0) ? &acc0 : (ms == 1) ? &acc1 : (ms == 2) ? &acc2 : &acc3;
            *acc = __builtin_amdgcn_mfma_f32_16x16x32_bf16(ah, bh, *acc, 0, 0, 0);
            *acc = __builtin_amdgcn_mfma_f32_16x16x32_bf16(ah, bl, *acc, 0, 0, 0);
            *acc = __builtin_amdgcn_mfma_f32_16x16x32_bf16(al, bh, *acc, 0, 0, 0);
        }
        __syncthreads();
    }

    const int col = n0 + lh;
#pragma unroll
    for (int ms = 0; ms < 4; ++ms){
        f32x4 a = (ms == 0) ? acc0 : (ms == 1) ? acc1 : (ms == 2) ? acc2 : acc3;
#pragma unroll
        for (int r = 0; r < 4; ++r){
            int row = m0 + ms * 16 + q * 4 + r;
            ext[(size_t)row * D_DIM + col] = a[r];
        }
    }
}

// ---------------- persistent recurrence: all 512 steps in one launch.
// WG j: feature-tile ft = j>>2 (16 features), batch group bg = j&3 (16 rows).
// NOTE: ext aliases out (no __restrict__ here on purpose).
__global__ __launch_bounds__(64, 1) void recurrence(
    const float* ext, const float* Wrec, float* out)
{
    __shared__ __align__(16) unsigned short st_hi[32 * 64 * 8];  // 32 KB
    __shared__ __align__(16) unsigned short st_lo[32 * 64 * 8];  // 32 KB
    // transpose scratch ALIASES st_* heads: live windows are disjoint
    // (tr: post-MFMA..pre-next-stage; st: post-stage..through-MFMA).
#define tr_h st_hi
#define tr_l st_lo

    const int L = threadIdx.x, lh = L & 15, q = L >> 4;
    const int j = blockIdx.x;
    const int ft = j >> 2, bg = j & 3;
    const int b0 = bg * 16;
    const int o  = ft * 16 + lh;
    const int shard = ft & 7;
    // this wave's output tile is contiguous in the fragment-order plane.
    // ull-granule offset (1 ull = 4 bf16): tile base in shorts is
    // bg*16384 + (ft>>1)*512 + (ft&1)*256  ->  /4 for ull index.
    const size_t toff64 = (size_t)bg * 4096 + (size_t)(ft >> 1) * 128
                        + (size_t)(ft & 1) * 64;

    // ---- pack W_rec B-fragments (hi/lo) into registers/AGPRs: 64 x short8
    short8 WH[32], WL[32];
#pragma unroll
    for (int kc = 0; kc < 32; ++kc)
        split8(Wrec + (size_t)(ft * 16 + lh) * D_DIM + kc * 32 + q * 8, WH[kc], WL[kc]);

    // ---- init: v0 = e0 -> plane 0 (transpose + coalesced agent stores)
    {
        float f[4];
#pragma unroll
        for (int r = 0; r < 4; ++r)
            f[r] = ext[(size_t)(b0 + q * 4 + r) * (TSTEPS * D_DIM) + o];
#pragma unroll
        for (int r = 0; r < 4; ++r){
            unsigned short h, l; split1(f[r], h, l);
            int s = (q * 4 + r) * 8 + ((lh >> 3) << 7) + (lh & 7);
            tr_h[s] = h; tr_l[s] = l;
        }
        asm volatile("s_waitcnt lgkmcnt(0)" ::: "memory");
        __builtin_amdgcn_sched_barrier(0);
        unsigned long long ph = *(const unsigned long long*)&tr_h[L * 4];
        unsigned long long pl = *(const unsigned long long*)&tr_l[L * 4];
        __hip_atomic_store(&g_s_hi[0][toff64 + L], ph,
                           __ATOMIC_RELAXED, __HIP_MEMORY_SCOPE_AGENT);
        __hip_atomic_store(&g_s_lo[0][toff64 + L], pl,
                           __ATOMIC_RELAXED, __HIP_MEMORY_SCOPE_AGENT);
    }
    asm volatile("" ::: "memory");          // stores strictly before prefetch

    float ev[4];                             // prefetch e_1
#pragma unroll
    for (int r = 0; r < 4; ++r)
        ev[r] = ext[(size_t)(b0 + q * 4 + r) * (TSTEPS * D_DIM) + D_DIM + o];

    asm volatile("s_waitcnt vmcnt(4)" ::: "memory");   // drain the 2 stores
    if (L == 0)
        __hip_atomic_fetch_add(&g_cnt[(bg * 8 + shard) * 32], 1u,
                               __ATOMIC_RELAXED, __HIP_MEMORY_SCOPE_AGENT);

#pragma unroll 1
    for (int k = 0; k < TSTEPS; ++k){
        const int p = k & 1;

        // ---- wait for state_k: group-local barrier (64 arrivals/round)
        for (;;){
            int s = (int)__hip_atomic_load(&g_cnt[(bg * 8 + (L & 7)) * 32],
                                           __ATOMIC_RELAXED, __HIP_MEMORY_SCOPE_AGENT);
            s += __shfl_xor(s, 1);
            s += __shfl_xor(s, 2);
            s += __shfl_xor(s, 4);
            if ((unsigned)s >= 64u * (unsigned)(k + 1)) break;
            __builtin_amdgcn_s_sleep(2);
        }
        __builtin_amdgcn_fence(__ATOMIC_ACQUIRE, "agent");

        // ---- stage state slab (own 16 batches, full K): issue all up front
        const unsigned short* gh = (const unsigned short*)&g_s_hi[p][0]
                                 + (size_t)bg * 16384 + L * 8;
        const unsigned short* gl = (const unsigned short*)&g_s_lo[p][0]
                                 + (size_t)bg * 16384 + L * 8;
#pragma unroll
        for (int kc = 0; kc < 32; ++kc){
            gl_lds16(gh + kc * 512, &st_hi[kc * 512]);
            gl_lds16(gl + kc * 512, &st_lo[kc * 512]);
        }

        // ---- 96 MFMAs in 4 chunks, each gated by counted vmcnt.
        // kc order is ascending throughout -> identical accumulation bits.
        f32x4 aHH = {0,0,0,0}, aHL = {0,0,0,0}, aLH = {0,0,0,0};
#define MCHUNK(G, VMS)                                                        \
        asm volatile("s_waitcnt vmcnt(" VMS ")" ::: "memory");                \
        __builtin_amdgcn_sched_barrier(0);                                    \
        _Pragma("unroll")                                                     \
        for (int kc = (G) * 8; kc < (G) * 8 + 8; ++kc){                       \
            short8 ah = *(const short8*)&st_hi[kc * 512 + L * 8];             \
            short8 al = *(const short8*)&st_lo[kc * 512 + L * 8];             \
            aHH = __builtin_amdgcn_mfma_f32_16x16x32_bf16(ah, WH[kc], aHH, 0, 0, 0); \
            aHL = __builtin_amdgcn_mfma_f32_16x16x32_bf16(ah, WL[kc], aHL, 0, 0, 0); \
            aLH = __builtin_amdgcn_mfma_f32_16x16x32_bf16(al, WH[kc], aLH, 0, 0, 0); \
        }
        MCHUNK(0, "48")
        MCHUNK(1, "32")
        MCHUNK(2, "16")
        MCHUNK(3, "0")
#undef MCHUNK

        if (k == TSTEPS - 1){
            // final state -> out[:,0,:] directly, full fp32 (no bf16 trip)
#pragma unroll
            for (int r = 0; r < 4; ++r){
                int b = b0 + q * 4 + r;
                out[(size_t)b * (TSTEPS * D_DIM) + o] =
                    fmaxf(aHH[r] + aHL[r] + aLH[r], 0.f);
            }
        } else {
            const int wp = p ^ 1;
            // transpose 16x16 tile into LDS scratch, then coalesced stores
#pragma unroll
            for (int r = 0; r < 4; ++r){
                float f = fmaxf(aHH[r] + aHL[r] + aLH[r], 0.f) + ev[r];
                unsigned short h, l; split1(f, h, l);
                int s = (q * 4 + r) * 8 + ((lh >> 3) << 7) + (lh & 7);
                tr_h[s] = h; tr_l[s] = l;
            }
            asm volatile("s_waitcnt lgkmcnt(0)" ::: "memory");
            __builtin_amdgcn_sched_barrier(0);
            {
                unsigned long long ph = *(const unsigned long long*)&tr_h[L * 4];
                unsigned long long pl = *(const unsigned long long*)&tr_l[L * 4];
                __hip_atomic_store(&g_s_hi[wp][toff64 + L], ph,
                                   __ATOMIC_RELAXED, __HIP_MEMORY_SCOPE_AGENT);
                __hip_atomic_store(&g_s_lo[wp][toff64 + L], pl,
                                   __ATOMIC_RELAXED, __HIP_MEMORY_SCOPE_AGENT);
            }
            asm volatile("" ::: "memory");  // stores strictly before prefetch
            if (k + 2 < TSTEPS){
                // prefetch e_{k+2}; latency hides under the barrier spin
#pragma unroll
                for (int r = 0; r < 4; ++r)
                    ev[r] = ext[(size_t)(b0 + q * 4 + r) * (TSTEPS * D_DIM)
                                + (size_t)(k + 2) * D_DIM + o];
                asm volatile("s_waitcnt vmcnt(4)" ::: "memory");  // 2 stores drained
            } else {
                asm volatile("s_waitcnt vmcnt(0)" ::: "memory");
            }
            if (L == 0)
                __hip_atomic_fetch_add(&g_cnt[(bg * 8 + shard) * 32], 1u,
                                       __ATOMIC_RELAXED, __HIP_MEMORY_SCOPE_AGENT);
        }
    }
#undef tr_h
#undef tr_l
}

// ---------------- out[:,1:,:] = 0 (out[:,0,:] holds the final state)
__global__ __launch_bounds__(256) void zero_rest(float* __restrict__ out)
{
    size_t i4 = (size_t)blockIdx.x * 256 + threadIdx.x;  // float4 index
    size_t f = i4 * 4;
    int t = (int)((f >> 10) & 511);
    if (t == 0) return;                                   // out[:,0,:] kept
    *(float4*)(out + f) = make_float4(0.f, 0.f, 0.f, 0.f);
}

extern "C" void kernel_launch(void* const* d_in, const int* in_sizes, int n_in,
                              void* d_out, int out_size, void* d_ws, size_t ws_size,
                              hipStream_t stream) {
    const float* x     = (const float*)d_in[0];   // [64][512][1024]
    const float* W_in  = (const float*)d_in[1];   // [1024][1024]
    const float* W_rec = (const float*)d_in[2];   // [1024][1024]
    float* out = (float*)d_out;

    // ext (fp32, [b][t][o]) lives in d_out — dead space until the end.
    float* ext = out;

    // 1) input projection (+ resets barrier counters for this replay)
    ext_gemm<<<dim3(16, 512), 256, 0, stream>>>(x, W_in, ext);

    // 2) all 512 recurrence steps in ONE persistent kernel
    recurrence<<<NWG, 64, 0, stream>>>(ext, W_rec, out);

    // 3) zero everything except out[:,0,:]
    zero_rest<<<32768, 256, 0, stream>>>(out);
}